// Round 3
// baseline (178.085 us; speedup 1.0000x reference)
//
#include <hip/hip_runtime.h>

// LiftSplatShoot, identity camera. Static facts (rounds 0-2):
//  - Only depth bins k=0..11 (d=4.0..9.5) survive (iz==0).
//  - Kept points land in ix in [81,118], iy in [89,112] (bbox w/ margin below).
//  - Along a ray x,y are monotone in d => <=1 merged entry per (ray,voxel).
//  - out[c,ix,iy] = sum over entries of weight * feat[c,ray].
// Round-3 structure: build inverse map (voxel -> padded entry list) in device
// globals, then one fused kernel writes all 82MB with coalesced float4 stores;
// active voxels sum their entry lists with an unrolled (ILP-8) loop.

#define NX0 200
#define NX1 200
#define NC 512
#define FH 24
#define FW 40
#define NRAY (FH * FW)
#define ND 12          // depth bins with iz==0
#define BX0 80         // active bbox with margin: ix in [80,120)
#define BNX 40
#define BY0 88         // iy in [88,114)
#define BNY 26
#define NVB (BNX * BNY)
#define CAP 40         // max entries per voxel (worst-case est ~31; 64 never clamped)

__device__ int  g_cnt[NVB];
__device__ int  g_n[NVB];            // count padded up to multiple of 8, <= CAP
__device__ int2 g_ent[NVB * CAP];    // {w as float bits, ray}

__global__ __launch_bounds__(1024)
void lss_build(const float* __restrict__ depth) {
#pragma clang fp contract(off)
    const int tid = threadIdx.x;
    for (int i = tid; i < NVB * CAP; i += 1024) g_ent[i] = make_int2(0, 0);
    for (int i = tid; i < NVB; i += 1024) g_cnt[i] = 0;
    __syncthreads();

    if (tid < NRAY) {
        const int ray = tid;
        const int w = ray % FW;
        const int h = ray / FW;

        // numpy float64 math, bit-exact (contract off, same op order as ref)
        const double a = 1.0 / 320.0;
        double u = (w == FW - 1) ? 639.0 : (double)w * (639.0 / 39.0);
        double v = (h == FH - 1) ? 383.0 : (double)h * (383.0 / 23.0);

        int   prev = -2;
        float wsum = 0.0f;
        for (int k = 0; k < ND; ++k) {
            double d  = 4.0 + 0.5 * (double)k;
            double x  = (u * d) * a - d;
            double y  = (v * d) * a - 0.5625 * d;
            double gx = (x + 50.0) * 2.0;
            double gy = (y + 50.0) * 2.0;
            int ix = (int)gx;
            int iy = (int)gy;
            int lv = -1;
            if (ix >= 0 && ix < NX0 && iy >= 0 && iy < NX1)
                lv = (ix - BX0) * BNY + (iy - BY0);
            float dv = depth[k * NRAY + ray];
            if (lv == prev) {
                wsum += dv;
            } else {
                if (prev >= 0) {
                    int slot = atomicAdd(&g_cnt[prev], 1);
                    if (slot < CAP)
                        g_ent[prev * CAP + slot] = make_int2(__float_as_int(wsum), ray);
                }
                prev = lv;
                wsum = dv;
            }
        }
        if (prev >= 0) {
            int slot = atomicAdd(&g_cnt[prev], 1);
            if (slot < CAP)
                g_ent[prev * CAP + slot] = make_int2(__float_as_int(wsum), ray);
        }
    }
    __syncthreads();
    for (int i = tid; i < NVB; i += 1024) {
        int n = g_cnt[i];
        if (n > CAP) n = CAP;
        g_n[i] = (n + 7) & ~7;       // padded entries are {0.0f, 0}: harmless
    }
}

// grid = (10, 512): blockIdx.y = channel, blockIdx.x covers the 200x200 plane.
// Each thread writes 4 float4 (16 elements); every output element written once.
__global__ __launch_bounds__(256)
void lss_gather(const float* __restrict__ feat, float* __restrict__ out) {
    const int c   = blockIdx.y;
    const int tid = threadIdx.x;
    const float* __restrict__ fc = feat + c * NRAY;
    float* __restrict__ oc = out + (size_t)c * (NX0 * NX1);

#pragma unroll
    for (int k = 0; k < 4; ++k) {
        const int q = blockIdx.x * 1024 + k * 256 + tid;   // float4 index in plane
        const int v = q * 4;
        if (v >= NX0 * NX1) continue;
        const int ix  = v / NX1;                            // magic-mul
        const int iy0 = v - ix * NX1;

        float4 r = make_float4(0.f, 0.f, 0.f, 0.f);
        if ((unsigned)(ix - BX0) < BNX) {
            float rr[4];
#pragma unroll
            for (int j = 0; j < 4; ++j) {
                float s = 0.f;
                const int iy = iy0 + j;
                if ((unsigned)(iy - BY0) < BNY) {
                    const int lv = (ix - BX0) * BNY + (iy - BY0);
                    const int n  = g_n[lv];
                    const int2* __restrict__ e = g_ent + lv * CAP;
#pragma unroll 8
                    for (int i = 0; i < n; ++i) {
                        int2 pe = e[i];
                        s += __int_as_float(pe.x) * fc[pe.y];
                    }
                }
                rr[j] = s;
            }
            r = make_float4(rr[0], rr[1], rr[2], rr[3]);
        }
        *(float4*)(oc + v) = r;
    }
}

extern "C" void kernel_launch(void* const* d_in, const int* in_sizes, int n_in,
                              void* d_out, int out_size, void* d_ws, size_t ws_size,
                              hipStream_t stream) {
    const float* feat  = (const float*)d_in[0];   // (1, 512, 24, 40)
    const float* depth = (const float*)d_in[1];   // (1, 80, 24, 40)
    float* out = (float*)d_out;                   // (1, 512, 200, 200)

    lss_build<<<1, 1024, 0, stream>>>(depth);
    lss_gather<<<dim3(10, NC), 256, 0, stream>>>(feat, out);
}

// Round 4
// 125.892 us; speedup vs baseline: 1.4146x; 1.4146x over previous
//
#include <hip/hip_runtime.h>

// LiftSplatShoot, identity camera. Static facts (rounds 0-3):
//  - Only depth bins k=0..11 (d=4.0..9.5) survive (iz==0).
//  - Kept points land in ix in [81,118], iy in [89,112] (margin below).
//  - Along a ray x,y are monotone in d => <=1 merged entry per (ray,voxel).
//  - out[c,ix,iy] = sum over entries of weight * feat[c,ray].
// Round-4 structure (fixes load imbalance of the fused gather):
//  1) build: inverse map voxel -> entry list (device globals).
//  2) active: one block per channel, feat in LDS, dense active patch to g_act.
//  3) write: uniform streaming kernel — zeros everywhere, bbox rows pull
//     their values from g_act (L2-resident). Nontemporal float4 stores.

#define NX0 200
#define NX1 200
#define NC 512
#define FH 24
#define FW 40
#define NRAY (FH * FW)
#define ND 12          // depth bins with iz==0
#define BX0 80         // active bbox with margin: ix in [80,120)
#define BNX 40
#define BY0 88         // iy in [88,114)
#define BNY 26
#define NVB (BNX * BNY)
#define CAP 40         // max entries per voxel (worst-case est ~31)

typedef float f32x4 __attribute__((ext_vector_type(4)));

__device__ int   g_cnt[NVB];
__device__ int   g_n[NVB];            // count padded to multiple of 8, <= CAP
__device__ int2  g_ent[NVB * CAP];    // {w as float bits, ray}
__device__ float g_act[NC * NVB];     // dense active patch, 2.13 MB

__global__ __launch_bounds__(1024)
void lss_build(const float* __restrict__ depth) {
#pragma clang fp contract(off)
    const int tid = threadIdx.x;
    for (int i = tid; i < NVB * CAP; i += 1024) g_ent[i] = make_int2(0, 0);
    for (int i = tid; i < NVB; i += 1024) g_cnt[i] = 0;
    __syncthreads();

    if (tid < NRAY) {
        const int ray = tid;
        const int w = ray % FW;
        const int h = ray / FW;

        // numpy float64 math, bit-exact (contract off, same op order as ref)
        const double a = 1.0 / 320.0;
        double u = (w == FW - 1) ? 639.0 : (double)w * (639.0 / 39.0);
        double v = (h == FH - 1) ? 383.0 : (double)h * (383.0 / 23.0);

        int   prev = -2;
        float wsum = 0.0f;
        for (int k = 0; k < ND; ++k) {
            double d  = 4.0 + 0.5 * (double)k;
            double x  = (u * d) * a - d;
            double y  = (v * d) * a - 0.5625 * d;
            double gx = (x + 50.0) * 2.0;
            double gy = (y + 50.0) * 2.0;
            int ix = (int)gx;
            int iy = (int)gy;
            int lv = -1;
            if (ix >= 0 && ix < NX0 && iy >= 0 && iy < NX1)
                lv = (ix - BX0) * BNY + (iy - BY0);
            float dv = depth[k * NRAY + ray];
            if (lv == prev) {
                wsum += dv;
            } else {
                if (prev >= 0) {
                    int slot = atomicAdd(&g_cnt[prev], 1);
                    if (slot < CAP)
                        g_ent[prev * CAP + slot] = make_int2(__float_as_int(wsum), ray);
                }
                prev = lv;
                wsum = dv;
            }
        }
        if (prev >= 0) {
            int slot = atomicAdd(&g_cnt[prev], 1);
            if (slot < CAP)
                g_ent[prev * CAP + slot] = make_int2(__float_as_int(wsum), ray);
        }
    }
    __syncthreads();
    for (int i = tid; i < NVB; i += 1024) {
        int n = g_cnt[i];
        if (n > CAP) n = CAP;
        g_n[i] = (n + 7) & ~7;        // padded entries are {0.0f, ray=0}: add 0
    }
}

// One block per channel: feat slice (960 floats) in LDS, compute all NVB
// active-patch sums for this channel.
__global__ __launch_bounds__(256)
void lss_active(const float* __restrict__ feat) {
    __shared__ float s_feat[NRAY];
    const int c   = blockIdx.x;
    const int tid = threadIdx.x;
    if (tid < NRAY / 4)
        ((f32x4*)s_feat)[tid] = ((const f32x4*)(feat + c * NRAY))[tid];
    __syncthreads();

    float* actc = g_act + c * NVB;
    for (int lv = tid; lv < NVB; lv += 256) {
        const int n = g_n[lv];
        const int2* __restrict__ e = g_ent + lv * CAP;
        float s = 0.0f;
#pragma unroll 8
        for (int i = 0; i < n; ++i) {
            int2 pe = e[i];
            s += __int_as_float(pe.x) * s_feat[pe.y];
        }
        actc[lv] = s;
    }
}

// Uniform streaming writer: every output float4 once; bbox rows read from
// g_act (L2-resident). Grid-stride.
__global__ __launch_bounds__(256)
void lss_write(float* __restrict__ out) {
    const int nq = NC * NX0 * NX1 / 4;           // 5,120,000 float4
    for (int q = blockIdx.x * 256 + threadIdx.x; q < nq; q += gridDim.x * 256) {
        const int base = q * 4;
        const int c    = base / (NX0 * NX1);     // magic-mul
        const int v    = base - c * (NX0 * NX1);
        const int ix   = v / NX1;
        const int iy0  = v - ix * NX1;

        f32x4 r = {0.f, 0.f, 0.f, 0.f};
        if ((unsigned)(ix - BX0) < BNX) {
            const float* __restrict__ a = g_act + c * NVB + (ix - BX0) * BNY;
#pragma unroll
            for (int j = 0; j < 4; ++j) {
                const int iy = iy0 + j;
                if ((unsigned)(iy - BY0) < BNY) r[j] = a[iy - BY0];
            }
        }
        __builtin_nontemporal_store(r, (f32x4*)(out + base));
    }
}

extern "C" void kernel_launch(void* const* d_in, const int* in_sizes, int n_in,
                              void* d_out, int out_size, void* d_ws, size_t ws_size,
                              hipStream_t stream) {
    const float* feat  = (const float*)d_in[0];   // (1, 512, 24, 40)
    const float* depth = (const float*)d_in[1];   // (1, 80, 24, 40)
    float* out = (float*)d_out;                   // (1, 512, 200, 200)

    lss_build<<<1, 1024, 0, stream>>>(depth);
    lss_active<<<NC, 256, 0, stream>>>(feat);
    lss_write<<<4096, 256, 0, stream>>>(out);
}

// Round 5
// 114.465 us; speedup vs baseline: 1.5558x; 1.0998x over previous
//
#include <hip/hip_runtime.h>
#include <stdint.h>

// LiftSplatShoot, identity camera — fully static geometry.
// Facts (validated rounds 1-4): only depth bins k=0..11 survive (iz==0);
// all kept points land at ix in [81,118], iy in [89,112]; out[c,ix,iy] =
// sum over points (k,ray)->(ix,iy) of depth[k,ray] * feat[c,ray].
// Round-5: the point->voxel map is computed at COMPILE TIME (constexpr CSR,
// replicating numpy float64 op order; an out-of-range voxel would be a
// constexpr OOB write => compile error). Runtime = memset + one fused kernel.

#define NX0 200
#define NX1 200
#define NC 512
#define FH 24
#define FW 40
#define NRAY (FH * FW)
#define ND 12          // depth bins with iz==0 (d = 4.0 .. 9.5)
#define BX0 80         // active bbox: ix in [80,120), iy in [88,114)
#define BNX 40
#define BY0 88
#define BNY 26
#define NVB (BNX * BNY)
#define NPTS (NRAY * ND)   // 11520 kept points, all in bbox

struct Tab {
    int      csr[NVB + 1];
    uint32_t ent[NPTS];    // low16 = k*960+ray (flat depth idx), high16 = ray
};

constexpr Tab build_tab() {
    Tab t{};
    int vox[NPTS] = {};
    for (int ray = 0; ray < NRAY; ++ray) {
        const int w = ray % FW, h = ray / FW;
        const double a = 1.0 / 320.0;
        // numpy linspace: y[i] = fl(i * fl(span/(n-1))), endpoint exact
        const double u = (w == FW - 1) ? 639.0 : (double)w * (639.0 / 39.0);
        const double v = (h == FH - 1) ? 383.0 : (double)h * (383.0 / 23.0);
        for (int k = 0; k < ND; ++k) {
            const double d = 4.0 + 0.5 * (double)k;       // arange(4,44,.5)
            const double x = (u * d) * a - d;             // pts @ inv(K).T
            const double y = (v * d) * a - 0.5625 * d;
            const int ix = (int)((x + 50.0) * 2.0);       // trunc toward zero
            const int iy = (int)((y + 50.0) * 2.0);
            vox[k * NRAY + ray] = (ix - BX0) * BNY + (iy - BY0);
        }
    }
    int cnt[NVB] = {};
    for (int i = 0; i < NPTS; ++i) ++cnt[vox[i]];         // OOB => compile err
    t.csr[0] = 0;
    for (int lv = 0; lv < NVB; ++lv) t.csr[lv + 1] = t.csr[lv] + cnt[lv];
    int pos[NVB] = {};
    for (int lv = 0; lv < NVB; ++lv) pos[lv] = t.csr[lv];
    for (int i = 0; i < NPTS; ++i) {
        const int lv  = vox[i];
        const int ray = i % NRAY;                          // i = k*NRAY + ray
        t.ent[pos[lv]++] = (uint32_t)i | ((uint32_t)ray << 16);
    }
    return t;
}

__constant__ Tab c_tab = build_tab();

// One block per channel. Stage active depth slice (12x960 = 46KB, contiguous
// head of the depth tensor) + feat row in LDS; each thread sums its voxels
// from the static CSR and writes directly into out (already zeroed).
__global__ __launch_bounds__(256)
void lss_fuse(const float* __restrict__ feat, const float* __restrict__ depth,
              float* __restrict__ out) {
    __shared__ float s_dep[NPTS];
    __shared__ float s_feat[NRAY];
    const int c   = blockIdx.x;
    const int tid = threadIdx.x;

    const float4* d4 = (const float4*)depth;               // k-major: first
    for (int i = tid; i < NPTS / 4; i += 256)              // NPTS floats are
        ((float4*)s_dep)[i] = d4[i];                       // exactly k=0..11
    if (tid < NRAY / 4)
        ((float4*)s_feat)[tid] = ((const float4*)(feat + c * NRAY))[tid];
    __syncthreads();

    float* oc = out + (size_t)c * (NX0 * NX1);
    for (int lv = tid; lv < NVB; lv += 256) {
        const int e0 = c_tab.csr[lv], e1 = c_tab.csr[lv + 1];
        float s = 0.0f;
        for (int e = e0; e < e1; ++e) {
            const uint32_t p = c_tab.ent[e];
            s += s_dep[p & 0xFFFFu] * s_feat[p >> 16];
        }
        const int ixo = lv / BNY;
        const int iyo = lv - ixo * BNY;
        oc[(BX0 + ixo) * NX1 + (BY0 + iyo)] = s;           // zeros elsewhere
    }
}

extern "C" void kernel_launch(void* const* d_in, const int* in_sizes, int n_in,
                              void* d_out, int out_size, void* d_ws, size_t ws_size,
                              hipStream_t stream) {
    const float* feat  = (const float*)d_in[0];   // (1, 512, 24, 40)
    const float* depth = (const float*)d_in[1];   // (1, 80, 24, 40)
    float* out = (float*)d_out;                   // (1, 512, 200, 200)

    hipMemsetAsync(out, 0, (size_t)out_size * sizeof(float), stream);
    lss_fuse<<<NC, 256, 0, stream>>>(feat, depth, out);
}